// Round 2
// 341.729 us; speedup vs baseline: 1.0947x; 1.0947x over previous
//
#include <hip/hip_runtime.h>
#include <math.h>

#define H 512
#define NH 8
#define NG 256

// ---- workspace layout (float offsets) ----
#define WS_QK   0          // 4096 floats : qk[j][h] pre-scaled by 1/8
#define WS_SB   4096       // 8 floats    : (k_b . q_h)/8
#define WS_SEG  4352       // 257 ints    : segment starts
#define WS_VWT  8192       // 262144      : v_w^T  [j][o]
#define WS_OWT  270336     // 262144      : o_w^T  [k][o]

// ---------------- fused setup kernel (verbatim from the passing round-0 version) ----------------
// blocks 0-1: segment starts; blocks 2-17: qk fold; blocks 18-529: weight transposes

__global__ __launch_bounds__(256) void k_setup(
    const int* __restrict__ batch, int N, int* __restrict__ seg,
    const float* __restrict__ k_w, const float* __restrict__ k_b,
    const float* __restrict__ query, float* __restrict__ qk, float* __restrict__ sb,
    const float* __restrict__ vw, const float* __restrict__ ow,
    float* __restrict__ vwt, float* __restrict__ owt) {
  __shared__ float tile[32][33];
  const int b = blockIdx.x;
  if (b < 2) {
    int g = b * 256 + threadIdx.x;
    if (g > NG) return;
    int lo = 0, hi = N;
    while (lo < hi) { int mid = (lo + hi) >> 1; if (batch[mid] < g) lo = mid + 1; else hi = mid; }
    seg[g] = lo;
  } else if (b < 18) {
    int gt = (b - 2) * 256 + threadIdx.x;       // 4096 values
    int h = gt >> 9, j = gt & 511;
    float a = 0.f;
#pragma unroll 8
    for (int d = 0; d < 64; ++d)
      a = fmaf(k_w[(size_t)(h * 64 + d) * H + j], query[h * 64 + d], a);
    qk[j * 8 + h] = a * 0.125f;                  // fold 1/sqrt(hd)
    if (gt < 8) {
      float s = 0.f;
      for (int d = 0; d < 64; ++d) s = fmaf(k_b[gt * 64 + d], query[gt * 64 + d], s);
      sb[gt] = s * 0.125f;
    }
  } else {
    int bb = b - 18;                             // 512 tiles
    const float* in  = (bb < 256) ? vw  : ow;
    float*       out = (bb < 256) ? vwt : owt;
    int tidx = bb & 255;
    int bx = tidx & 15, by = tidx >> 4;
    int tx = threadIdx.x & 31, ty = threadIdx.x >> 5;
#pragma unroll
    for (int k = 0; k < 4; ++k)
      tile[ty + 8 * k][tx] = in[(size_t)(by * 32 + ty + 8 * k) * H + bx * 32 + tx];
    __syncthreads();
#pragma unroll
    for (int k = 0; k < 4; ++k)
      out[(size_t)(bx * 32 + ty + 8 * k) * H + by * 32 + tx] = tile[tx][ty + 8 * k];
  }
}

// ---------------- main kernel: one block per graph, epilogue in-block ----------------

// add-with-DPP step: v += dpp_move(v); pure VALU, no LDS pipe
#define DPP_ADD(v, ctrl, rmask)                                                   \
  v += __int_as_float(__builtin_amdgcn_update_dpp(0, __float_as_int(v), ctrl,     \
                                                  rmask, 0xf, true))

__global__ __launch_bounds__(512, 2) void k_graph(
    const float* __restrict__ x, const float* __restrict__ qk, const float* __restrict__ sb,
    const int* __restrict__ seg, const float* __restrict__ vwt, const float* __restrict__ vb,
    const float* __restrict__ owt, const float* __restrict__ ob,
    const float* __restrict__ lng, const float* __restrict__ lnb,
    float* __restrict__ out) {
  const int g = blockIdx.x;
  const int t = threadIdx.x;
  const int lane = t & 63, wid = t >> 6;     // 8 waves
  const int s0 = seg[g], e0 = seg[g + 1];

  // LDS: 16K + 16K + 2K + small = ~34.6 KB
  __shared__ float TA[8][512];
  __shared__ float TB[8][512];
  __shared__ float den_lds[8][8];
  __shared__ float att[512];
  __shared__ float den_s[8], dinv_s[8];
  __shared__ float redA[8], redB[8];

  // per-lane column ownership: cols {4l..4l+3} and {256+4l..256+4l+3}
  float qk_r[8][8];   // [ci][h], pre-scaled by 1/8
#pragma unroll
  for (int ci = 0; ci < 8; ++ci) {
    int j = (ci < 4) ? (4 * lane + ci) : (256 + 4 * lane + ci - 4);
    const float4* row = (const float4*)(qk + j * 8);
    float4 q0 = row[0], q1 = row[1];
    qk_r[ci][0] = q0.x; qk_r[ci][1] = q0.y; qk_r[ci][2] = q0.z; qk_r[ci][3] = q0.w;
    qk_r[ci][4] = q1.x; qk_r[ci][5] = q1.y; qk_r[ci][6] = q1.z; qk_r[ci][7] = q1.w;
  }
  float sbr[8];
#pragma unroll
  for (int h = 0; h < 8; ++h) sbr[h] = sb[h];

  float T_r[8][8];    // [h][ci]
  float den[8];
#pragma unroll
  for (int h = 0; h < 8; ++h) {
    den[h] = 0.f;
#pragma unroll
    for (int ci = 0; ci < 8; ++ci) T_r[h][ci] = 0.f;
  }

  // ---- node loop: 8 waves stride by 8 nodes, double-prefetch ----
  const float4* x4 = (const float4*)x;
  int n = s0 + wid;
  float4 b0a, b0b, b1a, b1b;
  if (n < e0)     { size_t a = (size_t)n * 128 + lane;       b0a = x4[a]; b0b = x4[a + 64]; }
  if (n + 8 < e0) { size_t a = (size_t)(n + 8) * 128 + lane; b1a = x4[a]; b1b = x4[a + 64]; }

  for (; n < e0; n += 8) {
    float4 b2a, b2b;
    if (n + 16 < e0) { size_t a = (size_t)(n + 16) * 128 + lane; b2a = x4[a]; b2b = x4[a + 64]; }

    float xv[8] = {b0a.x, b0a.y, b0a.z, b0a.w, b0b.x, b0b.y, b0b.z, b0b.w};
    float pp[8] = {0.f, 0.f, 0.f, 0.f, 0.f, 0.f, 0.f, 0.f};
#pragma unroll
    for (int ci = 0; ci < 8; ++ci)
#pragma unroll
      for (int h = 0; h < 8; ++h) pp[h] = fmaf(xv[ci], qk_r[ci][h], pp[h]);

    // 64-lane sum, all-DPP (8 independent chains interleaved stepwise)
#pragma unroll
    for (int h = 0; h < 8; ++h) DPP_ADD(pp[h], 0x111, 0xf);   // row_shr:1
#pragma unroll
    for (int h = 0; h < 8; ++h) DPP_ADD(pp[h], 0x112, 0xf);   // row_shr:2
#pragma unroll
    for (int h = 0; h < 8; ++h) DPP_ADD(pp[h], 0x114, 0xf);   // row_shr:4
#pragma unroll
    for (int h = 0; h < 8; ++h) DPP_ADD(pp[h], 0x118, 0xf);   // row_shr:8
#pragma unroll
    for (int h = 0; h < 8; ++h) DPP_ADD(pp[h], 0x142, 0xa);   // row_bcast:15
#pragma unroll
    for (int h = 0; h < 8; ++h) DPP_ADD(pp[h], 0x143, 0xc);   // row_bcast:31

    float w[8];
#pragma unroll
    for (int h = 0; h < 8; ++h) {
      float s = __int_as_float(__builtin_amdgcn_readlane(__float_as_int(pp[h]), 63));
      w[h] = __expf(s + sbr[h]);        // softmax shift-invariant: no max needed
      den[h] += w[h];
    }
#pragma unroll
    for (int h = 0; h < 8; ++h)
#pragma unroll
      for (int ci = 0; ci < 8; ++ci) T_r[h][ci] = fmaf(w[h], xv[ci], T_r[h][ci]);

    b0a = b1a; b0b = b1b; b1a = b2a; b1b = b2b;
  }

  // ---- combine 8 waves: waves 0-3 serial-accumulate into TA, waves 4-7 into TB ----
  if (lane == 0) {
#pragma unroll
    for (int h = 0; h < 8; ++h) den_lds[wid][h] = den[h];
  }
  for (int s = 0; s < 4; ++s) {
    if (wid == s || wid == s + 4) {
      float (*T_)[512] = (wid < 4) ? TA : TB;
#pragma unroll
      for (int h = 0; h < 8; ++h) {
        float4 v0 = make_float4(T_r[h][0], T_r[h][1], T_r[h][2], T_r[h][3]);
        float4 v1 = make_float4(T_r[h][4], T_r[h][5], T_r[h][6], T_r[h][7]);
        float4* d0 = (float4*)&T_[h][4 * lane];
        float4* d1 = (float4*)&T_[h][256 + 4 * lane];
        if (s == 0) { *d0 = v0; *d1 = v1; }
        else {
          float4 o0 = *d0, o1 = *d1;
          o0.x += v0.x; o0.y += v0.y; o0.z += v0.z; o0.w += v0.w;
          o1.x += v1.x; o1.y += v1.y; o1.z += v1.z; o1.w += v1.w;
          *d0 = o0; *d1 = o1;
        }
      }
    }
    __syncthreads();
  }
  // merge TB into TA (thread t owns column t), fold denominators
#pragma unroll
  for (int h = 0; h < 8; ++h) TA[h][t] += TB[h][t];
  if (t < 8) {
    float d = 0.f;
#pragma unroll
    for (int w = 0; w < 8; ++w) d += den_lds[w][t];
    den_s[t] = d;
    dinv_s[t] = (d > 0.f) ? 1.f / d : 1.f;
  }
  __syncthreads();

  // ---- v-projection: attended = (v_w_h . T_h + den*v_b)/den ----
  const int h = t >> 6;                     // head of column t
  const float* Th = TA[h];
  float a = 0.f;
#pragma unroll 16
  for (int j = 0; j < H; ++j)
    a = fmaf(Th[j], vwt[(size_t)j * H + t], a);   // Th[j]: LDS broadcast; vwt: coalesced
  att[t] = (a + den_s[h] * vb[t]) * dinv_s[h];
  __syncthreads();

  // ---- o-projection ----
  float o = ob[t];
#pragma unroll 16
  for (int k = 0; k < H; ++k)
    o = fmaf(att[k], owt[(size_t)k * H + t], o);

  // ---- layernorm over 512 cols (8 waves) ----
  float r1 = o, r2 = o * o;
#pragma unroll
  for (int m = 1; m < 64; m <<= 1) { r1 += __shfl_xor(r1, m, 64); r2 += __shfl_xor(r2, m, 64); }
  if (lane == 0) { redA[wid] = r1; redB[wid] = r2; }
  __syncthreads();
  float S1 = 0.f, S2 = 0.f;
#pragma unroll
  for (int w = 0; w < 8; ++w) { S1 += redA[w]; S2 += redB[w]; }
  float mu = S1 * (1.f / 512.f);
  float var = S2 * (1.f / 512.f) - mu * mu;
  float rs = rsqrtf(var + 1e-5f);
  out[(size_t)g * H + t] = (o - mu) * rs * lng[t] + lnb[t];
}

// ---------------- launch ----------------

extern "C" void kernel_launch(void* const* d_in, const int* in_sizes, int n_in,
                              void* d_out, int out_size, void* d_ws, size_t ws_size,
                              hipStream_t stream) {
  const float* x     = (const float*)d_in[0];
  const int*   batch = (const int*)d_in[1];
  const float* query = (const float*)d_in[2];
  const float* k_w   = (const float*)d_in[3];
  const float* k_b   = (const float*)d_in[4];
  const float* v_w   = (const float*)d_in[5];
  const float* v_b   = (const float*)d_in[6];
  const float* o_w   = (const float*)d_in[7];
  const float* o_b   = (const float*)d_in[8];
  const float* ln_g  = (const float*)d_in[9];
  const float* ln_b  = (const float*)d_in[10];
  const int N = in_sizes[0] / H;            // in_sizes are ELEMENT counts (round-0 verified)

  float* ws  = (float*)d_ws;
  float* qk  = ws + WS_QK;
  float* sb  = ws + WS_SB;
  int*   seg = (int*)(ws + WS_SEG);
  float* vwt = ws + WS_VWT;
  float* owt = ws + WS_OWT;

  hipLaunchKernelGGL(k_setup, dim3(530), dim3(256), 0, stream,
                     batch, N, seg, k_w, k_b, query, qk, sb, v_w, o_w, vwt, owt);
  hipLaunchKernelGGL(k_graph, dim3(NG), dim3(512), 0, stream,
                     x, qk, sb, seg, vwt, v_b, owt, o_b, ln_g, ln_b, (float*)d_out);
}

// Round 4
// 339.898 us; speedup vs baseline: 1.1006x; 1.0054x over previous
//
#include <hip/hip_runtime.h>
#include <math.h>

#define H 512
#define NH 8
#define NG 256

typedef float f32x4 __attribute__((ext_vector_type(4)));

// ---- workspace layout (float/word offsets; float==uint32 size) ----
#define WS_QK   0          // 4096 floats : qk[j][h] pre-scaled by 1/8
#define WS_SB   4096       // 8 floats    : (k_b . q_h)/8
#define WS_SEG  4352       // 257 ints    : segment starts
#define WS_VWT  8192       // 131072 words: v_w^T packed bf16 row-pairs [256][512]
#define WS_OWT  139264     // 131072 words: o_w^T packed bf16 row-pairs [256][512]

// float -> bf16 (round-to-nearest-even), returned in low 16 bits
static __device__ __forceinline__ unsigned int bf16r(float f) {
  unsigned int u = __float_as_uint(f);
  return (u + 0x7FFFu + ((u >> 16) & 1u)) >> 16;
}

// ---------------- fused setup kernel ----------------
// blocks 0-1: segment starts; blocks 2-17: qk fold;
// blocks 18-529: weight transpose + bf16 pair-pack

__global__ __launch_bounds__(256) void k_setup(
    const int* __restrict__ batch, int N, int* __restrict__ seg,
    const float* __restrict__ k_w, const float* __restrict__ k_b,
    const float* __restrict__ query, float* __restrict__ qk, float* __restrict__ sb,
    const float* __restrict__ vw, const float* __restrict__ ow,
    unsigned int* __restrict__ vwt, unsigned int* __restrict__ owt) {
  __shared__ float tile[32][33];
  const int b = blockIdx.x;
  if (b < 2) {
    int g = b * 256 + threadIdx.x;
    if (g > NG) return;
    int lo = 0, hi = N;
    while (lo < hi) { int mid = (lo + hi) >> 1; if (batch[mid] < g) lo = mid + 1; else hi = mid; }
    seg[g] = lo;
  } else if (b < 18) {
    int gt = (b - 2) * 256 + threadIdx.x;       // 4096 values
    int h = gt >> 9, j = gt & 511;
    float a = 0.f;
#pragma unroll 8
    for (int d = 0; d < 64; ++d)
      a = fmaf(k_w[(size_t)(h * 64 + d) * H + j], query[h * 64 + d], a);
    qk[j * 8 + h] = a * 0.125f;                  // fold 1/sqrt(hd)
    if (gt < 8) {
      float s = 0.f;
      for (int d = 0; d < 64; ++d) s = fmaf(k_b[gt * 64 + d], query[gt * 64 + d], s);
      sb[gt] = s * 0.125f;
    }
  } else {
    int bb = b - 18;                             // 512 tiles (256 vw + 256 ow)
    const float*  in   = (bb < 256) ? vw  : ow;
    unsigned int* outw = (bb < 256) ? vwt : owt; // packed [256][512]
    int tidx = bb & 255;
    int bx = tidx & 15, by = tidx >> 4;
    int tx = threadIdx.x & 31, ty = threadIdx.x >> 5;   // ty in [0,8)
#pragma unroll
    for (int k = 0; k < 4; ++k)
      tile[ty + 8 * k][tx] = in[(size_t)(by * 32 + ty + 8 * k) * H + bx * 32 + tx];
    __syncthreads();
    // transposed element out[row][col] = tile[col&31][row&31]; pack rows (2wr, 2wr+1)
#pragma unroll
    for (int k = 0; k < 2; ++k) {
      int wr = ty + 8 * k;                       // [0,16) within tile
      unsigned int lo = bf16r(tile[tx][2 * wr]);
      unsigned int hi = bf16r(tile[tx][2 * wr + 1]);
      outw[(size_t)(bx * 16 + wr) * H + by * 32 + tx] = (hi << 16) | lo;
    }
  }
}

// ---------------- main kernel: one block per graph, epilogue in-block ----------------

// add-with-DPP step: v += dpp_move(v); pure VALU, no LDS pipe
#define DPP_ADD(v, ctrl, rmask)                                                   \
  v += __int_as_float(__builtin_amdgcn_update_dpp(0, __float_as_int(v), ctrl,     \
                                                  rmask, 0xf, true))

__global__ __launch_bounds__(512, 2) void k_graph(
    const float* __restrict__ x, const float* __restrict__ qk, const float* __restrict__ sb,
    const int* __restrict__ seg, const unsigned int* __restrict__ vwt,
    const float* __restrict__ vb, const unsigned int* __restrict__ owt,
    const float* __restrict__ ob, const float* __restrict__ lng,
    const float* __restrict__ lnb, float* __restrict__ out) {
  const int g = blockIdx.x;
  const int t = threadIdx.x;
  const int lane = t & 63, wid = t >> 6;     // 8 waves
  const int s0 = seg[g], e0 = seg[g + 1];

  // LDS: 16K + 16K + 2K + small = ~34.6 KB
  __shared__ float TA[8][512];
  __shared__ float TB[8][512];
  __shared__ float den_lds[8][8];
  __shared__ float att[512];
  __shared__ float den_s[8], dinv_s[8];
  __shared__ float redA[8], redB[8];

  // per-lane column ownership: cols {4l..4l+3} and {256+4l..256+4l+3}
  float qk_r[8][8];   // [ci][h], pre-scaled by 1/8
#pragma unroll
  for (int ci = 0; ci < 8; ++ci) {
    int j = (ci < 4) ? (4 * lane + ci) : (256 + 4 * lane + ci - 4);
    const float4* row = (const float4*)(qk + j * 8);
    float4 q0 = row[0], q1 = row[1];
    qk_r[ci][0] = q0.x; qk_r[ci][1] = q0.y; qk_r[ci][2] = q0.z; qk_r[ci][3] = q0.w;
    qk_r[ci][4] = q1.x; qk_r[ci][5] = q1.y; qk_r[ci][6] = q1.z; qk_r[ci][7] = q1.w;
  }
  float sbr[8];
#pragma unroll
  for (int h = 0; h < 8; ++h) sbr[h] = sb[h];

  float T_r[8][8];    // [h][ci]
  float den[8];
#pragma unroll
  for (int h = 0; h < 8; ++h) {
    den[h] = 0.f;
#pragma unroll
    for (int ci = 0; ci < 8; ++ci) T_r[h][ci] = 0.f;
  }

  // ---- node loop: 8 waves stride by 8 nodes, double-prefetch, non-temporal x ----
  const f32x4* x4 = (const f32x4*)x;
  int n = s0 + wid;
  f32x4 b0a, b0b, b1a, b1b;
  if (n < e0)     { size_t a = (size_t)n * 128 + lane;
                    b0a = __builtin_nontemporal_load(&x4[a]);
                    b0b = __builtin_nontemporal_load(&x4[a + 64]); }
  if (n + 8 < e0) { size_t a = (size_t)(n + 8) * 128 + lane;
                    b1a = __builtin_nontemporal_load(&x4[a]);
                    b1b = __builtin_nontemporal_load(&x4[a + 64]); }

  for (; n < e0; n += 8) {
    f32x4 b2a, b2b;
    if (n + 16 < e0) { size_t a = (size_t)(n + 16) * 128 + lane;
                       b2a = __builtin_nontemporal_load(&x4[a]);
                       b2b = __builtin_nontemporal_load(&x4[a + 64]); }

    float xv[8] = {b0a.x, b0a.y, b0a.z, b0a.w, b0b.x, b0b.y, b0b.z, b0b.w};
    float pp[8] = {0.f, 0.f, 0.f, 0.f, 0.f, 0.f, 0.f, 0.f};
#pragma unroll
    for (int ci = 0; ci < 8; ++ci)
#pragma unroll
      for (int h = 0; h < 8; ++h) pp[h] = fmaf(xv[ci], qk_r[ci][h], pp[h]);

    // 64-lane sum, all-DPP (8 independent chains interleaved stepwise)
#pragma unroll
    for (int h = 0; h < 8; ++h) DPP_ADD(pp[h], 0x111, 0xf);   // row_shr:1
#pragma unroll
    for (int h = 0; h < 8; ++h) DPP_ADD(pp[h], 0x112, 0xf);   // row_shr:2
#pragma unroll
    for (int h = 0; h < 8; ++h) DPP_ADD(pp[h], 0x114, 0xf);   // row_shr:4
#pragma unroll
    for (int h = 0; h < 8; ++h) DPP_ADD(pp[h], 0x118, 0xf);   // row_shr:8
#pragma unroll
    for (int h = 0; h < 8; ++h) DPP_ADD(pp[h], 0x142, 0xa);   // row_bcast:15
#pragma unroll
    for (int h = 0; h < 8; ++h) DPP_ADD(pp[h], 0x143, 0xc);   // row_bcast:31

    float w[8];
#pragma unroll
    for (int h = 0; h < 8; ++h) {
      float s = __int_as_float(__builtin_amdgcn_readlane(__float_as_int(pp[h]), 63));
      w[h] = __expf(s + sbr[h]);        // softmax shift-invariant: no max needed
      den[h] += w[h];
    }
#pragma unroll
    for (int h = 0; h < 8; ++h)
#pragma unroll
      for (int ci = 0; ci < 8; ++ci) T_r[h][ci] = fmaf(w[h], xv[ci], T_r[h][ci]);

    b0a = b1a; b0b = b1b; b1a = b2a; b1b = b2b;
  }

  // ---- combine 8 waves: waves 0-3 serial-accumulate into TA, waves 4-7 into TB ----
  if (lane == 0) {
#pragma unroll
    for (int h = 0; h < 8; ++h) den_lds[wid][h] = den[h];
  }
  for (int s = 0; s < 4; ++s) {
    if (wid == s || wid == s + 4) {
      float (*T_)[512] = (wid < 4) ? TA : TB;
#pragma unroll
      for (int h = 0; h < 8; ++h) {
        float4 v0 = make_float4(T_r[h][0], T_r[h][1], T_r[h][2], T_r[h][3]);
        float4 v1 = make_float4(T_r[h][4], T_r[h][5], T_r[h][6], T_r[h][7]);
        float4* d0 = (float4*)&T_[h][4 * lane];
        float4* d1 = (float4*)&T_[h][256 + 4 * lane];
        if (s == 0) { *d0 = v0; *d1 = v1; }
        else {
          float4 o0 = *d0, o1 = *d1;
          o0.x += v0.x; o0.y += v0.y; o0.z += v0.z; o0.w += v0.w;
          o1.x += v1.x; o1.y += v1.y; o1.z += v1.z; o1.w += v1.w;
          *d0 = o0; *d1 = o1;
        }
      }
    }
    __syncthreads();
  }
  // merge TB into TA (thread t owns column t), fold denominators
#pragma unroll
  for (int h = 0; h < 8; ++h) TA[h][t] += TB[h][t];
  if (t < 8) {
    float d = 0.f;
#pragma unroll
    for (int w = 0; w < 8; ++w) d += den_lds[w][t];
    den_s[t] = d;
    dinv_s[t] = (d > 0.f) ? 1.f / d : 1.f;
  }
  __syncthreads();

  // ---- v-projection: attended = (v_w_h . T_h + den*v_b)/den  (bf16 packed pairs) ----
  const int h = t >> 6;                     // head of column t
  const float* Th = TA[h];
  float a = 0.f;
#pragma unroll 8
  for (int jw = 0; jw < H / 2; ++jw) {
    unsigned int u = vwt[(size_t)jw * H + t];
    float w0 = __uint_as_float(u << 16);           // row 2jw
    float w1 = __uint_as_float(u & 0xFFFF0000u);   // row 2jw+1
    a = fmaf(Th[2 * jw], w0, a);
    a = fmaf(Th[2 * jw + 1], w1, a);
  }
  att[t] = (a + den_s[h] * vb[t]) * dinv_s[h];
  __syncthreads();

  // ---- o-projection (bf16 packed pairs) ----
  float o = ob[t];
#pragma unroll 8
  for (int kw = 0; kw < H / 2; ++kw) {
    unsigned int u = owt[(size_t)kw * H + t];
    float w0 = __uint_as_float(u << 16);
    float w1 = __uint_as_float(u & 0xFFFF0000u);
    o = fmaf(att[2 * kw], w0, o);
    o = fmaf(att[2 * kw + 1], w1, o);
  }

  // ---- layernorm over 512 cols (8 waves) ----
  float r1 = o, r2 = o * o;
#pragma unroll
  for (int m = 1; m < 64; m <<= 1) { r1 += __shfl_xor(r1, m, 64); r2 += __shfl_xor(r2, m, 64); }
  if (lane == 0) { redA[wid] = r1; redB[wid] = r2; }
  __syncthreads();
  float S1 = 0.f, S2 = 0.f;
#pragma unroll
  for (int w = 0; w < 8; ++w) { S1 += redA[w]; S2 += redB[w]; }
  float mu = S1 * (1.f / 512.f);
  float var = S2 * (1.f / 512.f) - mu * mu;
  float rs = rsqrtf(var + 1e-5f);
  out[(size_t)g * H + t] = (o - mu) * rs * lng[t] + lnb[t];
}

// ---------------- launch ----------------

extern "C" void kernel_launch(void* const* d_in, const int* in_sizes, int n_in,
                              void* d_out, int out_size, void* d_ws, size_t ws_size,
                              hipStream_t stream) {
  const float* x     = (const float*)d_in[0];
  const int*   batch = (const int*)d_in[1];
  const float* query = (const float*)d_in[2];
  const float* k_w   = (const float*)d_in[3];
  const float* k_b   = (const float*)d_in[4];
  const float* v_w   = (const float*)d_in[5];
  const float* v_b   = (const float*)d_in[6];
  const float* o_w   = (const float*)d_in[7];
  const float* o_b   = (const float*)d_in[8];
  const float* ln_g  = (const float*)d_in[9];
  const float* ln_b  = (const float*)d_in[10];
  const int N = in_sizes[0] / H;            // in_sizes are ELEMENT counts (verified)

  float* ws  = (float*)d_ws;
  float* qk  = ws + WS_QK;
  float* sb  = ws + WS_SB;
  int*   seg = (int*)(ws + WS_SEG);
  unsigned int* vwt = (unsigned int*)(ws + WS_VWT);
  unsigned int* owt = (unsigned int*)(ws + WS_OWT);

  hipLaunchKernelGGL(k_setup, dim3(530), dim3(256), 0, stream,
                     batch, N, seg, k_w, k_b, query, qk, sb, v_w, o_w, vwt, owt);
  hipLaunchKernelGGL(k_graph, dim3(NG), dim3(512), 0, stream,
                     x, qk, sb, seg, vwt, v_b, owt, o_b, ln_g, ln_b, (float*)d_out);
}